// Round 5
// baseline (694.033 us; speedup 1.0000x reference)
//
#include <hip/hip_runtime.h>
#include <hip/hip_bf16.h>
#include <stdint.h>

// MozafariMNIST2018 forward. B=4096, T=15, HW=784, F1=500, F3=10.
// Output layout (float32, concatenated):
//   spk1 [4096*15*500] @ 0
//   thr1 [4096*15*500] @ 30720000
//   pot3 [4096*15*10]  @ 61440000
//   cls  [4096]        @ 62054400
//
// Key identity: inp[b,t,p] is cumulative binary in t:
//   inp[b,t,p] == (t0[b,p] <= t),  t0 = 15 - sum_t inp  (4 bits).
// Pipeline:
//   k_t0:    stream input once (192.7MB) -> nibble-packed t0 (1.64MB)
//   k_prep:  w1 fp32 -> f16 [512][800] prepack (0.82MB)
//   k_main:  barrier-free MFMA GEMM; A-frags from w1pack (L2-resident),
//            B-frags rebuilt in-register from t0 nibbles; fp32 acc;
//            near-threshold exact fp32 fixup (R4-proven); writes spk1/thr1.
//   k_conv3: pot3 = spk1 x w3 via f16 MFMA (err <= 0.13 << 12.64 tol)
//   k_winner
// Scratch: t0nib+w1pack live in the pot3 output region (1638400+819200 =
// 2457600 B exactly); conv3 overwrites it afterwards. d_ws unused.

typedef _Float16     f16x8 __attribute__((ext_vector_type(8)));
typedef float        f32x4 __attribute__((ext_vector_type(4)));
typedef unsigned int u32x4 __attribute__((ext_vector_type(4)));

#define CONV1_T   26.3424f
#define FIX_DELTA 0.05f
#define KDIM 784
#define F1   500

// ------------------------------------------------------------------
// k_t0: t0nib[b][p] (4-bit) = 15 - sum_t inp[b,t,p]; pad p>=784 -> 15.
// One thread = one output dword (8 pixels). 4096*100 threads.
// ------------------------------------------------------------------
__global__ __launch_bounds__(256)
void k_t0(const float* __restrict__ inp, unsigned int* __restrict__ t0nib)
{
    const int gid = blockIdx.x * 256 + threadIdx.x;   // < 409600
    const int b   = gid / 100;
    const int p8  = gid % 100;
    if (p8 >= 98) { t0nib[gid] = 0xFFFFFFFFu; return; }   // pad pixels

    const float* base = inp + (size_t)b * 11760 + p8 * 8;
    float cnt[8];
    #pragma unroll
    for (int e = 0; e < 8; ++e) cnt[e] = 0.f;
    #pragma unroll
    for (int t = 0; t < 15; ++t) {
        const f32x4 v0 = *(const f32x4*)(base + t * 784);
        const f32x4 v1 = *(const f32x4*)(base + t * 784 + 4);
        #pragma unroll
        for (int e = 0; e < 4; ++e) { cnt[e] += v0[e]; cnt[e + 4] += v1[e]; }
    }
    unsigned int d = 0;
    #pragma unroll
    for (int e = 0; e < 8; ++e) {
        const unsigned int t0 = 15u - (unsigned int)cnt[e];   // 0..14
        d |= (t0 & 15u) << (4 * e);
    }
    t0nib[gid] = d;
}

// ------------------------------------------------------------------
// k_prep: w1 [500x784] fp32 -> f16 w1pack [512][800], zero-padded.
// ------------------------------------------------------------------
__global__ __launch_bounds__(256)
void k_prep(const float* __restrict__ w1, _Float16* __restrict__ w1pack)
{
    const int gid = blockIdx.x * 256 + threadIdx.x;   // < 51200
    const int f   = gid / 100;
    const int k8  = gid % 100;
    f16x8 v;
    #pragma unroll
    for (int e = 0; e < 8; ++e) {
        const int k = k8 * 8 + e;
        v[e] = (f < F1 && k < KDIM) ? (_Float16)w1[f * KDIM + k] : (_Float16)0.f;
    }
    *(f16x8*)(w1pack + (size_t)f * 800 + k8 * 8) = v;
}

// exact fp32 recompute for near-threshold elements (rare); same summation
// order as the R4-proven fix_dot (a[k]*w[k], k ascending, 4-way split).
__device__ __attribute__((noinline))
float fix_dot_t0(const unsigned char* __restrict__ nib,
                 const float* __restrict__ w, int t)
{
    float s0 = 0.f, s1 = 0.f, s2 = 0.f, s3 = 0.f;
    for (int k = 0; k < KDIM; k += 4) {
        const unsigned int b0 = nib[k >> 1];
        const unsigned int b1 = nib[(k >> 1) + 1];
        const float a0 = ((int)(b0 & 15u)  <= t) ? 1.f : 0.f;
        const float a1 = ((int)(b0 >> 4)   <= t) ? 1.f : 0.f;
        const float a2 = ((int)(b1 & 15u)  <= t) ? 1.f : 0.f;
        const float a3 = ((int)(b1 >> 4)   <= t) ? 1.f : 0.f;
        s0 = fmaf(a0, w[k],     s0);
        s1 = fmaf(a1, w[k + 1], s1);
        s2 = fmaf(a2, w[k + 2], s2);
        s3 = fmaf(a3, w[k + 3], s3);
    }
    return (s0 + s1) + (s2 + s3);
}

// ------------------------------------------------------------------
// k_main: per wave: 4 batches x 128 f x all 15 t. Barrier-free, no LDS.
// MFMA 16x16x32_f16: A[m=f-local, k] from w1pack (global/L2, 16B/lane),
// B[k, n=t] rebuilt from t0 nibbles (7 VALU per reg). acc fp32.
// grid: 1024 blocks x 256 thr = 4096 waves = 1024 batch-quads x 4 f-groups.
// ------------------------------------------------------------------
__global__ __launch_bounds__(256, 2)
void k_main(const float* __restrict__ w1,
            const unsigned char* __restrict__ t0nib,
            const _Float16* __restrict__ w1pack,
            float* __restrict__ spk1, float* __restrict__ thr1)
{
    const int tid  = threadIdx.x;
    const int lane = tid & 63;
    const int wid  = tid >> 6;
    const int gw   = blockIdx.x * 4 + wid;    // 0..4095
    const int q    = gw >> 2;                 // batch quad 0..1023
    const int fg   = gw & 3;                  // f-group 0..3
    const int b0   = q * 4;
    const int fb0  = fg * 128;
    const int lr   = lane & 15;               // A: m-row / B: n-col (=t) / C: col
    const int kg   = lane >> 4;               // k-group 0..3

    // A-frag pointers per f-tile (halfs)
    const _Float16* aptr[8];
    #pragma unroll
    for (int ft = 0; ft < 8; ++ft)
        aptr[ft] = w1pack + (size_t)(fb0 + ft * 16 + lr) * 800 + kg * 8;

    // t0 dword pointers per batch (per-lane k-slice baked in)
    const unsigned char* tptr[4];
    #pragma unroll
    for (int j = 0; j < 4; ++j)
        tptr[j] = t0nib + (size_t)(b0 + j) * 400 + kg * 4;

    f32x4 acc[8][4];
    #pragma unroll
    for (int i = 0; i < 8; ++i)
        #pragma unroll
        for (int j = 0; j < 4; ++j) acc[i][j] = {0.f, 0.f, 0.f, 0.f};

    for (int ks = 0; ks < 25; ++ks) {
        // ---- B-frags: 4 batches, from nibbles (k = ks*32 + kg*8 + e)
        f16x8 bf[4];
        #pragma unroll
        for (int j = 0; j < 4; ++j) {
            const unsigned int d = *(const unsigned int*)(tptr[j] + ks * 16);
            u32x4 br;
            #pragma unroll
            for (int h = 0; h < 4; ++h) {
                const unsigned int n0 = (d >> (8 * h))     & 15u;
                const unsigned int n1 = (d >> (8 * h + 4)) & 15u;
                br[h] = (n0 <= (unsigned)lr ? 0x3C00u     : 0u)
                      | (n1 <= (unsigned)lr ? 0x3C000000u : 0u);
            }
            bf[j] = __builtin_bit_cast(f16x8, br);
        }
        // ---- A-frags + MFMA: 8 f-tiles x 4 batches
        #pragma unroll
        for (int ft = 0; ft < 8; ++ft) {
            const f16x8 a = *(const f16x8*)(aptr[ft] + ks * 32);
            acc[ft][0] = __builtin_amdgcn_mfma_f32_16x16x32_f16(a, bf[0], acc[ft][0], 0, 0, 0);
            acc[ft][1] = __builtin_amdgcn_mfma_f32_16x16x32_f16(a, bf[1], acc[ft][1], 0, 0, 0);
            acc[ft][2] = __builtin_amdgcn_mfma_f32_16x16x32_f16(a, bf[2], acc[ft][2], 0, 0, 0);
            acc[ft][3] = __builtin_amdgcn_mfma_f32_16x16x32_f16(a, bf[3], acc[ft][3], 0, 0, 0);
        }
    }

    // ---- epilogue: C col = lr (= t), row = kg*4 + r (f-local). Fire+write.
    const int t = lr;
    if (t < 15) {
        #pragma unroll
        for (int ft = 0; ft < 8; ++ft) {
            #pragma unroll
            for (int j = 0; j < 4; ++j) {
                const long long m = (long long)(b0 + j) * 15 + t;
                #pragma unroll
                for (int r = 0; r < 4; ++r) {
                    const int f = fb0 + ft * 16 + kg * 4 + r;
                    if (f < F1) {
                        float p = acc[ft][j][r];
                        if (__builtin_expect(fabsf(p - CONV1_T) < FIX_DELTA, 0))
                            p = fix_dot_t0(t0nib + (size_t)(b0 + j) * 400,
                                           w1 + (size_t)f * KDIM, t);
                        const bool fire = (p >= CONV1_T);
                        thr1[m * F1 + f] = fire ? p : 0.f;
                        spk1[m * F1 + f] = fire ? 1.f : 0.f;
                    }
                }
            }
        }
    }
}

// ------------------------------------------------------------------
// k_conv3: pot3[row,g] = sum_f spk1[row,f]*w3[g,f] via 16x16x32 f16 MFMA.
// One wave = 16 rows. A[m=row, k=f] = spk1 (0/1, f16-exact);
// B[k=f, n=g] = w3[g,f] (f16, err <= 0.13 << 12.64 tolerance).
// ------------------------------------------------------------------
__global__ __launch_bounds__(256)
void k_conv3(const float* __restrict__ spk1, const float* __restrict__ w3,
             float* __restrict__ pot3)
{
    const int tid  = threadIdx.x;
    const int lane = tid & 63;
    const int wid  = tid >> 6;
    const int gw   = blockIdx.x * 4 + wid;    // 0..3839
    const long long row0 = (long long)gw * 16;
    const int lr = lane & 15;
    const int kg = lane >> 4;
    const int n  = (lr < 10) ? lr : 0;        // g (junk cols discarded)

    const float* arow = spk1 + (row0 + lr) * F1;
    const float* brow = w3 + (size_t)n * F1;

    f32x4 acc = {0.f, 0.f, 0.f, 0.f};
    #pragma unroll
    for (int ks = 0; ks < 16; ++ks) {
        const int k0 = ks * 32 + kg * 8;
        f16x8 a, b;
        if (k0 + 8 <= F1) {
            const f32x4 a0 = *(const f32x4*)(arow + k0);
            const f32x4 a1 = *(const f32x4*)(arow + k0 + 4);
            const f32x4 b0 = *(const f32x4*)(brow + k0);
            const f32x4 b1 = *(const f32x4*)(brow + k0 + 4);
            #pragma unroll
            for (int e = 0; e < 4; ++e) {
                a[e] = (_Float16)a0[e]; a[e + 4] = (_Float16)a1[e];
                b[e] = (_Float16)b0[e]; b[e + 4] = (_Float16)b1[e];
            }
        } else {
            #pragma unroll
            for (int e = 0; e < 8; ++e) {
                const int k = k0 + e;
                a[e] = (k < F1) ? (_Float16)arow[k] : (_Float16)0.f;
                b[e] = (k < F1) ? (_Float16)brow[k] : (_Float16)0.f;
            }
        }
        acc = __builtin_amdgcn_mfma_f32_16x16x32_f16(a, b, acc, 0, 0, 0);
    }
    if (lr < 10) {
        #pragma unroll
        for (int r = 0; r < 4; ++r) {
            const long long m = row0 + kg * 4 + r;
            pot3[m * 10 + lr] = acc[r];
        }
    }
}

// ------------------------------------------------------------------
// k_winner: winner-take-all per batch, faithful to reference algebra.
// ------------------------------------------------------------------
__global__ __launch_bounds__(256)
void k_winner(const float* __restrict__ pot3, float* __restrict__ outCls, int nB)
{
    const int b = blockIdx.x * 256 + threadIdx.x;
    if (b >= nB) return;
    const float* p = pot3 + (long long)b * 150 + 140;   // t = 14 row

    float pv[10], s[10];
    float mv = 0.f;
    #pragma unroll
    for (int g = 0; g < 10; ++g) {
        const float v = p[g];
        pv[g] = v;
        s[g]  = (v > 0.f) ? 1.f : ((v < 0.f) ? -1.f : 0.f);
        mv = fmaxf(mv, s[g] * v);
    }
    const float vbig = mv * 15.f;
    float bm = -INFINITY; int bi = 0;
    #pragma unroll
    for (int g = 0; g < 10; ++g) {
        const float tot = s[g] * pv[g] + s[g] * vbig;
        if (tot > bm) { bm = tot; bi = g; }
    }
    outCls[b] = (bm != 0.f) ? (float)bi : -1.f;
}

// ------------------------------------------------------------------
extern "C" void kernel_launch(void* const* d_in, const int* in_sizes, int n_in,
                              void* d_out, int out_size, void* d_ws, size_t ws_size,
                              hipStream_t stream)
{
    const float* inp = (const float*)d_in[0];
    const float* w1  = (const float*)d_in[1];
    const float* w3  = (const float*)d_in[2];

    float* out  = (float*)d_out;
    float* spk1 = out;
    float* thr1 = out + 30720000LL;
    float* pot3 = out + 61440000LL;
    float* cls  = out + 62054400LL;

    // Scratch inside the pot3 region (2457600 B): t0nib 1638400 B +
    // w1pack 819200 B. Both are dead before k_conv3 overwrites the region.
    unsigned int*  t0nib  = (unsigned int*)pot3;
    _Float16*      w1pack = (_Float16*)((char*)pot3 + 1638400);

    k_t0    <<<1600, 256, 0, stream>>>(inp, t0nib);
    k_prep  <<<200,  256, 0, stream>>>(w1, w1pack);
    k_main  <<<1024, 256, 0, stream>>>(w1, (const unsigned char*)t0nib, w1pack,
                                       spk1, thr1);
    k_conv3 <<<960,  256, 0, stream>>>(spk1, w3, pot3);
    k_winner<<<16,   256, 0, stream>>>(pot3, cls, 4096);
}

// Round 6
// 370.039 us; speedup vs baseline: 1.8756x; 1.8756x over previous
//
#include <hip/hip_runtime.h>
#include <hip/hip_bf16.h>
#include <stdint.h>

// MozafariMNIST2018 forward. B=4096, T=15, HW=784, F1=500, F3=10.
// Output layout (float32, concatenated):
//   spk1 [4096*15*500] @ 0
//   thr1 [4096*15*500] @ 30720000
//   pot3 [4096*15*10]  @ 61440000
//   cls  [4096]        @ 62054400
//
// Identity: inp[b,t,p] = (t0[b,p] <= t), t0 = 15 - sum_t inp (4 bits).
// Pipeline:
//   k_t0:   stream input once (193MB) -> nibble-packed t0 (1.64MB)
//   k_prep: w1 fp32 -> f16 in EXACT B-fragment order (one coalesced 1KB
//           dwordx4 chunk per (f-tile, k-step)) -> 800KB, L2-resident
//   k_main: barrier-free, LDS-free MFMA GEMM. A-frags (spikes) rebuilt
//           in-register from t0 nibbles; B-frags one coalesced 16B/lane
//           load; C lanes = f (coalesced stores). fp32 acc + exact fp32
//           fixup for |p-THR|<0.05 (proven R4/R5). Writes spk1/thr1.
//   k_conv3 (streaming, R3-proven), k_winner.
// Scratch (2457600 B = t0nib 1638400 + w1frag 819200): d_ws if big
// enough, else the pot3 region (dead until conv3 overwrites it).

typedef _Float16     f16x8 __attribute__((ext_vector_type(8)));
typedef float        f32x4 __attribute__((ext_vector_type(4)));
typedef unsigned int u32x4 __attribute__((ext_vector_type(4)));

#define CONV1_T   26.3424f
#define FIX_DELTA 0.05f
#define KDIM 784
#define F1   500

// ------------------------------------------------------------------
// k_t0: t0nib[b][p] (4-bit) = 15 - sum_t inp[b,t,p]; pad p>=784 -> 15.
// ------------------------------------------------------------------
__global__ __launch_bounds__(256)
void k_t0(const float* __restrict__ inp, unsigned int* __restrict__ t0nib)
{
    const int gid = blockIdx.x * 256 + threadIdx.x;   // < 409600
    const int b   = gid / 100;
    const int p8  = gid % 100;
    if (p8 >= 98) { t0nib[gid] = 0xFFFFFFFFu; return; }

    const float* base = inp + (size_t)b * 11760 + p8 * 8;
    float cnt[8];
    #pragma unroll
    for (int e = 0; e < 8; ++e) cnt[e] = 0.f;
    #pragma unroll
    for (int t = 0; t < 15; ++t) {
        const f32x4 v0 = *(const f32x4*)(base + t * 784);
        const f32x4 v1 = *(const f32x4*)(base + t * 784 + 4);
        #pragma unroll
        for (int e = 0; e < 4; ++e) { cnt[e] += v0[e]; cnt[e + 4] += v1[e]; }
    }
    unsigned int d = 0;
    #pragma unroll
    for (int e = 0; e < 8; ++e) {
        const unsigned int t0 = 15u - (unsigned int)cnt[e];   // 0..14
        d |= (t0 & 15u) << (4 * e);
    }
    t0nib[gid] = d;
}

// ------------------------------------------------------------------
// k_prep: w1 -> f16 w1frag in B-fragment order.
// chunk (fnt, ks): 64 lanes x 16B contiguous; lane = kg*16+lr holds
// B[k=ks*32+kg*8+e][f=fnt*16+lr].
// ------------------------------------------------------------------
__global__ __launch_bounds__(256)
void k_prep(const float* __restrict__ w1, _Float16* __restrict__ w1frag)
{
    const int gid  = blockIdx.x * 256 + threadIdx.x;   // < 51200 = 32*25*64
    const int lane = gid & 63;
    const int ks   = (gid >> 6) % 25;
    const int fnt  = gid / 1600;                       // f-tile 0..31
    const int lr   = lane & 15;
    const int kg   = lane >> 4;
    const int f    = fnt * 16 + lr;

    f16x8 v;
    #pragma unroll
    for (int e = 0; e < 8; ++e) {
        const int k = ks * 32 + kg * 8 + e;
        v[e] = (f < F1 && k < KDIM) ? (_Float16)w1[f * KDIM + k] : (_Float16)0.f;
    }
    *(f16x8*)(w1frag + (size_t)gid * 8) = v;
}

// exact fp32 recompute for near-threshold elements (rare)
__device__ __attribute__((noinline))
float fix_dot_t0(const unsigned char* __restrict__ nib,
                 const float* __restrict__ w, int t)
{
    float s0 = 0.f, s1 = 0.f, s2 = 0.f, s3 = 0.f;
    for (int k = 0; k < KDIM; k += 4) {
        const unsigned int b0 = nib[k >> 1];
        const unsigned int b1 = nib[(k >> 1) + 1];
        const float a0 = ((int)(b0 & 15u) <= t) ? 1.f : 0.f;
        const float a1 = ((int)(b0 >> 4)  <= t) ? 1.f : 0.f;
        const float a2 = ((int)(b1 & 15u) <= t) ? 1.f : 0.f;
        const float a3 = ((int)(b1 >> 4)  <= t) ? 1.f : 0.f;
        s0 = fmaf(a0, w[k],     s0);
        s1 = fmaf(a1, w[k + 1], s1);
        s2 = fmaf(a2, w[k + 2], s2);
        s3 = fmaf(a3, w[k + 3], s3);
    }
    return (s0 + s1) + (s2 + s3);
}

// rebuild one A-frag (spikes) from a t0 nibble dword: a[e] = (nib_e <= t)
__device__ __forceinline__
f16x8 rebuild_a(unsigned int d, int t)
{
    u32x4 br;
    #pragma unroll
    for (int h = 0; h < 4; ++h) {
        const unsigned int n0 = (d >> (8 * h))     & 15u;
        const unsigned int n1 = (d >> (8 * h + 4)) & 15u;
        br[h] = (n0 <= (unsigned)t ? 0x3C00u     : 0u)
              | (n1 <= (unsigned)t ? 0x3C000000u : 0u);
    }
    return __builtin_bit_cast(f16x8, br);
}

// ------------------------------------------------------------------
// k_main: per wave 64 rows x 64 f. Barrier-free, LDS-free.
// A[row=lr][k=kg*8+e] rebuilt from t0; B one coalesced 16B/lane load;
// C col=lr (f, coalesced stores), row=kg*4+r.
// grid: 1920 blocks x 256 thr = 7680 waves = 960 rowTiles x 8 fGroups.
// ------------------------------------------------------------------
__global__ __launch_bounds__(256, 2)
void k_main(const float* __restrict__ w1,
            const unsigned char* __restrict__ t0nib,
            const _Float16* __restrict__ w1frag,
            float* __restrict__ spk1, float* __restrict__ thr1)
{
    const int tid  = threadIdx.x;
    const int lane = tid & 63;
    const int wid  = tid >> 6;
    const int gw   = blockIdx.x * 4 + wid;    // 0..7679
    const int rowTile = gw >> 3;              // 0..959
    const int fgrp    = gw & 7;               // 0..7
    const long long rowBase = (long long)rowTile * 64;
    const int fb0 = fgrp * 64;
    const int lr  = lane & 15;
    const int kg  = lane >> 4;

    // per-fm t0 pointers (row = rowBase + fm*16 + lr) and t values
    const unsigned char* tp[4];
    int tv[4];
    #pragma unroll
    for (int fm = 0; fm < 4; ++fm) {
        const long long m = rowBase + fm * 16 + lr;
        const int b = (int)(m / 15);
        tv[fm] = (int)(m % 15);
        tp[fm] = t0nib + (size_t)b * 400 + kg * 4;
    }
    // per-fn B chunk base (lane's 16B baked in): chunk (fnt, ks) at
    // ((fnt*25+ks)*64+lane)*16 bytes
    const char* bp[4];
    #pragma unroll
    for (int fn = 0; fn < 4; ++fn) {
        const int fnt = (fb0 >> 4) + fn;
        bp[fn] = (const char*)w1frag + ((size_t)(fnt * 25) * 64 + lane) * 16;
    }

    f32x4 acc[4][4];
    #pragma unroll
    for (int i = 0; i < 4; ++i)
        #pragma unroll
        for (int j = 0; j < 4; ++j) acc[i][j] = {0.f, 0.f, 0.f, 0.f};

    // ---- reg double-buffer: t0 dwords + B frags
    unsigned int d0[4];
    f16x8 b0[4];
    #pragma unroll
    for (int fm = 0; fm < 4; ++fm) d0[fm] = *(const unsigned int*)(tp[fm]);
    #pragma unroll
    for (int fn = 0; fn < 4; ++fn) b0[fn] = *(const f16x8*)(bp[fn]);

    for (int ks = 0; ks < 25; ++ks) {
        unsigned int d1[4];
        f16x8 b1[4];
        if (ks < 24) {
            #pragma unroll
            for (int fm = 0; fm < 4; ++fm)
                d1[fm] = *(const unsigned int*)(tp[fm] + (ks + 1) * 16);
            #pragma unroll
            for (int fn = 0; fn < 4; ++fn)
                b1[fn] = *(const f16x8*)(bp[fn] + (size_t)(ks + 1) * 1024);
        }

        f16x8 a[4];
        #pragma unroll
        for (int fm = 0; fm < 4; ++fm) a[fm] = rebuild_a(d0[fm], tv[fm]);

        #pragma unroll
        for (int fm = 0; fm < 4; ++fm) {
            acc[fm][0] = __builtin_amdgcn_mfma_f32_16x16x32_f16(a[fm], b0[0], acc[fm][0], 0, 0, 0);
            acc[fm][1] = __builtin_amdgcn_mfma_f32_16x16x32_f16(a[fm], b0[1], acc[fm][1], 0, 0, 0);
            acc[fm][2] = __builtin_amdgcn_mfma_f32_16x16x32_f16(a[fm], b0[2], acc[fm][2], 0, 0, 0);
            acc[fm][3] = __builtin_amdgcn_mfma_f32_16x16x32_f16(a[fm], b0[3], acc[fm][3], 0, 0, 0);
        }

        if (ks < 24) {
            #pragma unroll
            for (int fm = 0; fm < 4; ++fm) d0[fm] = d1[fm];
            #pragma unroll
            for (int fn = 0; fn < 4; ++fn) b0[fn] = b1[fn];
        }
    }

    // ---- epilogue: fixup + fire + coalesced writes
    #pragma unroll
    for (int fm = 0; fm < 4; ++fm) {
        #pragma unroll
        for (int fn = 0; fn < 4; ++fn) {
            const int f = fb0 + fn * 16 + lr;
            if (f < F1) {
                #pragma unroll
                for (int r = 0; r < 4; ++r) {
                    const long long m = rowBase + fm * 16 + kg * 4 + r;
                    float p = acc[fm][fn][r];
                    if (__builtin_expect(fabsf(p - CONV1_T) < FIX_DELTA, 0)) {
                        const long long bb = m / 15;
                        const int tt = (int)(m % 15);
                        p = fix_dot_t0(t0nib + (size_t)bb * 400,
                                       w1 + (size_t)f * KDIM, tt);
                    }
                    const bool fire = (p >= CONV1_T);
                    thr1[m * F1 + f] = fire ? p : 0.f;
                    spk1[m * F1 + f] = fire ? 1.f : 0.f;
                }
            }
        }
    }
}

// ------------------------------------------------------------------
// k_conv3: pot3[row,g] = sum_f spk1[row,f]*w3[g,f]. One wave/row,
// 8 rows/block, coalesced f32x4 loads, shuffle reduce.
// ------------------------------------------------------------------
__global__ __launch_bounds__(512)
void k_conv3(const float* __restrict__ spk1, const float* __restrict__ w3,
             float* __restrict__ pot3)
{
    __shared__ float sw[5000];
    const int tid = threadIdx.x;
    for (int i = tid; i < 5000; i += 512) sw[i] = w3[i];
    __syncthreads();

    const int lane = tid & 63;
    const int wr   = tid >> 6;
    const long long row = (long long)blockIdx.x * 8 + wr;
    const float* sr = spk1 + row * F1;

    float ps[10];
    #pragma unroll
    for (int g = 0; g < 10; ++g) ps[g] = 0.f;

    const int f0 = lane * 8;
    if (f0 < F1) {
        const f32x4 v0 = *(const f32x4*)(sr + f0);
        f32x4 v1 = {0.f, 0.f, 0.f, 0.f};
        if (f0 + 4 < F1) v1 = *(const f32x4*)(sr + f0 + 4);
        const float v[8] = {v0[0], v0[1], v0[2], v0[3], v1[0], v1[1], v1[2], v1[3]};
        #pragma unroll
        for (int e = 0; e < 8; ++e) {
            const int f = f0 + e;
            if (f < F1) {
                const float s = v[e];
                #pragma unroll
                for (int g = 0; g < 10; ++g) ps[g] += s * sw[g * F1 + f];
            }
        }
    }
    #pragma unroll
    for (int g = 0; g < 10; ++g) {
        float t = ps[g];
        #pragma unroll
        for (int off = 32; off; off >>= 1) t += __shfl_xor(t, off);
        if (lane == 0) pot3[row * 10 + g] = t;
    }
}

// ------------------------------------------------------------------
// k_winner: winner-take-all per batch, faithful to reference algebra.
// ------------------------------------------------------------------
__global__ __launch_bounds__(256)
void k_winner(const float* __restrict__ pot3, float* __restrict__ outCls, int nB)
{
    const int b = blockIdx.x * 256 + threadIdx.x;
    if (b >= nB) return;
    const float* p = pot3 + (long long)b * 150 + 140;   // t = 14 row

    float pv[10], s[10];
    float mv = 0.f;
    #pragma unroll
    for (int g = 0; g < 10; ++g) {
        const float v = p[g];
        pv[g] = v;
        s[g]  = (v > 0.f) ? 1.f : ((v < 0.f) ? -1.f : 0.f);
        mv = fmaxf(mv, s[g] * v);
    }
    const float vbig = mv * 15.f;
    float bm = -INFINITY; int bi = 0;
    #pragma unroll
    for (int g = 0; g < 10; ++g) {
        const float tot = s[g] * pv[g] + s[g] * vbig;
        if (tot > bm) { bm = tot; bi = g; }
    }
    outCls[b] = (bm != 0.f) ? (float)bi : -1.f;
}

// ------------------------------------------------------------------
extern "C" void kernel_launch(void* const* d_in, const int* in_sizes, int n_in,
                              void* d_out, int out_size, void* d_ws, size_t ws_size,
                              hipStream_t stream)
{
    const float* inp = (const float*)d_in[0];
    const float* w1  = (const float*)d_in[1];
    const float* w3  = (const float*)d_in[2];

    float* out  = (float*)d_out;
    float* spk1 = out;
    float* thr1 = out + 30720000LL;
    float* pot3 = out + 61440000LL;
    float* cls  = out + 62054400LL;

    // Scratch: t0nib (1638400 B) + w1frag (819200 B) = 2457600 B.
    char* scratch = (ws_size >= 2457600) ? (char*)d_ws : (char*)pot3;
    unsigned int* t0nib  = (unsigned int*)scratch;
    _Float16*     w1frag = (_Float16*)(scratch + 1638400);

    k_t0    <<<1600, 256, 0, stream>>>(inp, t0nib);
    k_prep  <<<200,  256, 0, stream>>>(w1, w1frag);
    k_main  <<<1920, 256, 0, stream>>>(w1, (const unsigned char*)t0nib, w1frag,
                                       spk1, thr1);
    k_conv3 <<<7680, 512, 0, stream>>>(spk1, w3, pot3);
    k_winner<<<16,   256, 0, stream>>>(pot3, cls, 4096);
}

// Round 7
// 291.376 us; speedup vs baseline: 2.3819x; 1.2700x over previous
//
#include <hip/hip_runtime.h>
#include <hip/hip_bf16.h>
#include <stdint.h>

// MozafariMNIST2018 forward. B=4096, T=15, HW=784, F1=500, F3=10.
// Output layout (float32, concatenated):
//   spk1 [4096*15*500] @ 0
//   thr1 [4096*15*500] @ 30720000
//   pot3 [4096*15*10]  @ 61440000
//   cls  [4096]        @ 62054400
//
// Identity: inp[b,t,p] = (t0[b,p] <= t), t0 = 15 - sum_t inp (4 bits).
// Pipeline:
//   k_t0:    stream input once (193MB) -> nibble-packed t0 (1.64MB)
//   k_prep:  w1 fp32 -> f16 B-fragment order, [ks][fnt] chunk-major so a
//            wave's 4 fn chunks are contiguous (1 ptr + imm offsets)
//   k_main:  barrier-free LDS-free MFMA GEMM; A (spikes) rebuilt in-reg
//            from t0 nibbles; B 2-deep reg prefetch; fp32 acc + exact
//            fp32 fixup for |p-THR|<0.05; coalesced spk1/thr1 stores.
//   k_conv3: MFMA over K=500 (R5-verified), one wave = 16 rows.
//   k_winner.
// Scratch (2457600 B): d_ws if big enough, else pot3 region (dead until
// conv3 overwrites it).

typedef _Float16     f16x8 __attribute__((ext_vector_type(8)));
typedef float        f32x4 __attribute__((ext_vector_type(4)));
typedef unsigned int u32x4 __attribute__((ext_vector_type(4)));

#define CONV1_T   26.3424f
#define FIX_DELTA 0.05f
#define KDIM 784
#define F1   500

// ------------------------------------------------------------------
// k_t0: t0nib[b][p] (4-bit) = 15 - sum_t inp[b,t,p]; pad p>=784 -> 15.
// ------------------------------------------------------------------
__global__ __launch_bounds__(256)
void k_t0(const float* __restrict__ inp, unsigned int* __restrict__ t0nib)
{
    const int gid = blockIdx.x * 256 + threadIdx.x;   // < 409600
    const int b   = gid / 100;
    const int p8  = gid % 100;
    if (p8 >= 98) { t0nib[gid] = 0xFFFFFFFFu; return; }

    const float* base = inp + (size_t)b * 11760 + p8 * 8;
    float cnt[8];
    #pragma unroll
    for (int e = 0; e < 8; ++e) cnt[e] = 0.f;
    #pragma unroll
    for (int t = 0; t < 15; ++t) {
        const f32x4 v0 = *(const f32x4*)(base + t * 784);
        const f32x4 v1 = *(const f32x4*)(base + t * 784 + 4);
        #pragma unroll
        for (int e = 0; e < 4; ++e) { cnt[e] += v0[e]; cnt[e + 4] += v1[e]; }
    }
    unsigned int d = 0;
    #pragma unroll
    for (int e = 0; e < 8; ++e) {
        const unsigned int t0 = 15u - (unsigned int)cnt[e];   // 0..14
        d |= (t0 & 15u) << (4 * e);
    }
    t0nib[gid] = d;
}

// ------------------------------------------------------------------
// k_prep: w1 -> f16 w1frag, chunk (ks, fnt) at ((ks*32+fnt)*64+lane)*16 B.
// lane = kg*16+lr holds B[k=ks*32+kg*8+e][f=fnt*16+lr].
// ------------------------------------------------------------------
__global__ __launch_bounds__(256)
void k_prep(const float* __restrict__ w1, _Float16* __restrict__ w1frag)
{
    const int gid  = blockIdx.x * 256 + threadIdx.x;   // < 51200 = 25*32*64
    const int lane = gid & 63;
    const int fnt  = (gid >> 6) & 31;
    const int ks   = gid >> 11;                        // 0..24
    const int lr   = lane & 15;
    const int kg   = lane >> 4;
    const int f    = fnt * 16 + lr;

    f16x8 v;
    #pragma unroll
    for (int e = 0; e < 8; ++e) {
        const int k = ks * 32 + kg * 8 + e;
        v[e] = (f < F1 && k < KDIM) ? (_Float16)w1[f * KDIM + k] : (_Float16)0.f;
    }
    *(f16x8*)(w1frag + (size_t)gid * 8) = v;
}

// exact fp32 recompute for near-threshold elements (rare)
__device__ __attribute__((noinline))
float fix_dot_t0(const unsigned char* __restrict__ nib,
                 const float* __restrict__ w, int t)
{
    float s0 = 0.f, s1 = 0.f, s2 = 0.f, s3 = 0.f;
    for (int k = 0; k < KDIM; k += 4) {
        const unsigned int b0 = nib[k >> 1];
        const unsigned int b1 = nib[(k >> 1) + 1];
        const float a0 = ((int)(b0 & 15u) <= t) ? 1.f : 0.f;
        const float a1 = ((int)(b0 >> 4)  <= t) ? 1.f : 0.f;
        const float a2 = ((int)(b1 & 15u) <= t) ? 1.f : 0.f;
        const float a3 = ((int)(b1 >> 4)  <= t) ? 1.f : 0.f;
        s0 = fmaf(a0, w[k],     s0);
        s1 = fmaf(a1, w[k + 1], s1);
        s2 = fmaf(a2, w[k + 2], s2);
        s3 = fmaf(a3, w[k + 3], s3);
    }
    return (s0 + s1) + (s2 + s3);
}

// rebuild one A-frag (spikes) from a t0 nibble dword: a[e] = (nib_e <= t)
__device__ __forceinline__
f16x8 rebuild_a(unsigned int d, int t)
{
    u32x4 br;
    #pragma unroll
    for (int h = 0; h < 4; ++h) {
        const unsigned int n0 = (d >> (8 * h))     & 15u;
        const unsigned int n1 = (d >> (8 * h + 4)) & 15u;
        br[h] = (n0 <= (unsigned)t ? 0x3C00u     : 0u)
              | (n1 <= (unsigned)t ? 0x3C000000u : 0u);
    }
    return __builtin_bit_cast(f16x8, br);
}

// ------------------------------------------------------------------
// k_main: per wave 64 rows x 64 f. Barrier-free, LDS-free.
// A[row=lr][k=kg*8+e] rebuilt from t0; B: one addr, 4 fn at imm offsets
// 0/1024/2048/3072, advanced 32768 B/step, 2-deep reg prefetch.
// grid: 1920 blocks x 256 thr = 7680 waves = 960 rowTiles x 8 fGroups.
// ------------------------------------------------------------------
__global__ __launch_bounds__(256)
void k_main(const float* __restrict__ w1,
            const unsigned char* __restrict__ t0nib,
            const _Float16* __restrict__ w1frag,
            float* __restrict__ spk1, float* __restrict__ thr1)
{
    const int tid  = threadIdx.x;
    const int lane = tid & 63;
    const int wid  = tid >> 6;
    const int gw   = blockIdx.x * 4 + wid;    // 0..7679
    const int rowTile = gw >> 3;              // 0..959
    const int fgrp    = gw & 7;               // 0..7 -> 64-f group
    const long long rowBase = (long long)rowTile * 64;
    const int fb0 = fgrp * 64;
    const int lr  = lane & 15;
    const int kg  = lane >> 4;

    // per-fm t0 pointers (row = rowBase + fm*16 + lr) and t values
    const unsigned char* tp[4];
    int tv[4];
    #pragma unroll
    for (int fm = 0; fm < 4; ++fm) {
        const long long m = rowBase + fm * 16 + lr;
        const int b = (int)(m / 15);
        tv[fm] = (int)(m % 15);
        tp[fm] = t0nib + (size_t)b * 400 + kg * 4;
    }
    // B: one pointer, 4 fn at imm offsets; +32768 B per k-step
    const char* bptr = (const char*)w1frag + (size_t)fgrp * 4096
                     + (size_t)lane * 16;

    f32x4 acc[4][4];
    #pragma unroll
    for (int i = 0; i < 4; ++i)
        #pragma unroll
        for (int j = 0; j < 4; ++j) acc[i][j] = {0.f, 0.f, 0.f, 0.f};

    // ---- prefetch: B 2-deep, t0 1-deep
    f16x8 bA[4], bB[4];
    unsigned int d0[4];
    #pragma unroll
    for (int fn = 0; fn < 4; ++fn) {
        bA[fn] = *(const f16x8*)(bptr + fn * 1024);
        bB[fn] = *(const f16x8*)(bptr + 32768 + fn * 1024);
    }
    #pragma unroll
    for (int fm = 0; fm < 4; ++fm) d0[fm] = *(const unsigned int*)(tp[fm]);
    bptr += 2 * 32768;

    for (int ks = 0; ks < 25; ++ks) {
        // issue prefetches for ks+2 (B) and ks+1 (t0)
        f16x8 bC[4];
        unsigned int d1[4];
        if (ks + 2 < 25) {
            #pragma unroll
            for (int fn = 0; fn < 4; ++fn)
                bC[fn] = *(const f16x8*)(bptr + fn * 1024);
            bptr += 32768;
        }
        if (ks + 1 < 25) {
            #pragma unroll
            for (int fm = 0; fm < 4; ++fm)
                d1[fm] = *(const unsigned int*)(tp[fm] + (ks + 1) * 16);
        }

        // rebuild A + MFMA
        #pragma unroll
        for (int fm = 0; fm < 4; ++fm) {
            const f16x8 a = rebuild_a(d0[fm], tv[fm]);
            acc[fm][0] = __builtin_amdgcn_mfma_f32_16x16x32_f16(a, bA[0], acc[fm][0], 0, 0, 0);
            acc[fm][1] = __builtin_amdgcn_mfma_f32_16x16x32_f16(a, bA[1], acc[fm][1], 0, 0, 0);
            acc[fm][2] = __builtin_amdgcn_mfma_f32_16x16x32_f16(a, bA[2], acc[fm][2], 0, 0, 0);
            acc[fm][3] = __builtin_amdgcn_mfma_f32_16x16x32_f16(a, bA[3], acc[fm][3], 0, 0, 0);
        }

        // rotate buffers
        #pragma unroll
        for (int fn = 0; fn < 4; ++fn) { bA[fn] = bB[fn]; bB[fn] = bC[fn]; }
        #pragma unroll
        for (int fm = 0; fm < 4; ++fm) d0[fm] = d1[fm];
    }

    // ---- epilogue: fixup + fire + coalesced writes
    #pragma unroll
    for (int fm = 0; fm < 4; ++fm) {
        #pragma unroll
        for (int fn = 0; fn < 4; ++fn) {
            const int f = fb0 + fn * 16 + lr;
            if (f < F1) {
                #pragma unroll
                for (int r = 0; r < 4; ++r) {
                    const long long m = rowBase + fm * 16 + kg * 4 + r;
                    float p = acc[fm][fn][r];
                    if (__builtin_expect(fabsf(p - CONV1_T) < FIX_DELTA, 0)) {
                        const long long bb = m / 15;
                        const int tt = (int)(m % 15);
                        p = fix_dot_t0(t0nib + (size_t)bb * 400,
                                       w1 + (size_t)f * KDIM, tt);
                    }
                    const bool fire = (p >= CONV1_T);
                    thr1[m * F1 + f] = fire ? p : 0.f;
                    spk1[m * F1 + f] = fire ? 1.f : 0.f;
                }
            }
        }
    }
}

// ------------------------------------------------------------------
// k_conv3: pot3[row,g] = sum_f spk1[row,f]*w3[g,f] via 16x16x32 f16 MFMA.
// One wave = 16 rows (R5-verified). A = spk1 (0/1, f16-exact);
// B[k=f][n=g] = w3[g,f] (f16, err <= 0.13 << 12.64 tolerance).
// ------------------------------------------------------------------
__global__ __launch_bounds__(256)
void k_conv3(const float* __restrict__ spk1, const float* __restrict__ w3,
             float* __restrict__ pot3)
{
    const int tid  = threadIdx.x;
    const int lane = tid & 63;
    const int wid  = tid >> 6;
    const int gw   = blockIdx.x * 4 + wid;    // 0..3839
    const long long row0 = (long long)gw * 16;
    const int lr = lane & 15;
    const int kg = lane >> 4;
    const int n  = (lr < 10) ? lr : 0;        // g (junk cols discarded)

    const float* arow = spk1 + (row0 + lr) * F1;
    const float* brow = w3 + (size_t)n * F1;

    f32x4 acc = {0.f, 0.f, 0.f, 0.f};
    #pragma unroll
    for (int ks = 0; ks < 16; ++ks) {
        const int k0 = ks * 32 + kg * 8;
        f16x8 a, b;
        if (k0 + 8 <= F1) {
            const f32x4 a0 = *(const f32x4*)(arow + k0);
            const f32x4 a1 = *(const f32x4*)(arow + k0 + 4);
            const f32x4 b0 = *(const f32x4*)(brow + k0);
            const f32x4 b1 = *(const f32x4*)(brow + k0 + 4);
            #pragma unroll
            for (int e = 0; e < 4; ++e) {
                a[e] = (_Float16)a0[e]; a[e + 4] = (_Float16)a1[e];
                b[e] = (_Float16)b0[e]; b[e + 4] = (_Float16)b1[e];
            }
        } else {
            #pragma unroll
            for (int e = 0; e < 8; ++e) {
                const int k = k0 + e;
                a[e] = (k < F1) ? (_Float16)arow[k] : (_Float16)0.f;
                b[e] = (k < F1) ? (_Float16)brow[k] : (_Float16)0.f;
            }
        }
        acc = __builtin_amdgcn_mfma_f32_16x16x32_f16(a, b, acc, 0, 0, 0);
    }
    if (lr < 10) {
        #pragma unroll
        for (int r = 0; r < 4; ++r) {
            const long long m = row0 + kg * 4 + r;
            pot3[m * 10 + lr] = acc[r];
        }
    }
}

// ------------------------------------------------------------------
// k_winner: winner-take-all per batch, faithful to reference algebra.
// ------------------------------------------------------------------
__global__ __launch_bounds__(256)
void k_winner(const float* __restrict__ pot3, float* __restrict__ outCls, int nB)
{
    const int b = blockIdx.x * 256 + threadIdx.x;
    if (b >= nB) return;
    const float* p = pot3 + (long long)b * 150 + 140;   // t = 14 row

    float pv[10], s[10];
    float mv = 0.f;
    #pragma unroll
    for (int g = 0; g < 10; ++g) {
        const float v = p[g];
        pv[g] = v;
        s[g]  = (v > 0.f) ? 1.f : ((v < 0.f) ? -1.f : 0.f);
        mv = fmaxf(mv, s[g] * v);
    }
    const float vbig = mv * 15.f;
    float bm = -INFINITY; int bi = 0;
    #pragma unroll
    for (int g = 0; g < 10; ++g) {
        const float tot = s[g] * pv[g] + s[g] * vbig;
        if (tot > bm) { bm = tot; bi = g; }
    }
    outCls[b] = (bm != 0.f) ? (float)bi : -1.f;
}

// ------------------------------------------------------------------
extern "C" void kernel_launch(void* const* d_in, const int* in_sizes, int n_in,
                              void* d_out, int out_size, void* d_ws, size_t ws_size,
                              hipStream_t stream)
{
    const float* inp = (const float*)d_in[0];
    const float* w1  = (const float*)d_in[1];
    const float* w3  = (const float*)d_in[2];

    float* out  = (float*)d_out;
    float* spk1 = out;
    float* thr1 = out + 30720000LL;
    float* pot3 = out + 61440000LL;
    float* cls  = out + 62054400LL;

    // Scratch: t0nib (1638400 B) + w1frag (819200 B) = 2457600 B.
    char* scratch = (ws_size >= 2457600) ? (char*)d_ws : (char*)pot3;
    unsigned int* t0nib  = (unsigned int*)scratch;
    _Float16*     w1frag = (_Float16*)(scratch + 1638400);

    k_t0    <<<1600, 256, 0, stream>>>(inp, t0nib);
    k_prep  <<<200,  256, 0, stream>>>(w1, w1frag);
    k_main  <<<1920, 256, 0, stream>>>(w1, (const unsigned char*)t0nib, w1frag,
                                       spk1, thr1);
    k_conv3 <<<960,  256, 0, stream>>>(spk1, w3, pot3);
    k_winner<<<16,   256, 0, stream>>>(pot3, cls, 4096);
}